// Round 1
// baseline (738.208 us; speedup 1.0000x reference)
//
#include <hip/hip_runtime.h>
#include <math.h>

// ---------------- degree / dinv ----------------
__global__ void deg_init(float* __restrict__ deg, int n) {
    int v = blockIdx.x * blockDim.x + threadIdx.x;
    if (v < n) deg[v] = 1.0f;  // self-loop
}

__global__ void deg_edges(const int* __restrict__ dst, float* __restrict__ deg, int E) {
    int e = blockIdx.x * blockDim.x + threadIdx.x;
    if (e < E) atomicAdd(&deg[dst[e]], 1.0f);
}

__global__ void deg_fin(float* __restrict__ deg, int n) {
    int v = blockIdx.x * blockDim.x + threadIdx.x;
    if (v < n) deg[v] = 1.0f / sqrtf(deg[v]);
}

// ---------------- GEMM: Y[n,64] = X[n,K] @ W[K,64] ----------------
template <int K>
__global__ __launch_bounds__(256) void gemm_rm64(const float* __restrict__ X,
                                                 const float* __restrict__ W,
                                                 float* __restrict__ Y, int n) {
    __shared__ float Ws[K * 64];
    for (int i = threadIdx.x; i < K * 64; i += 256) Ws[i] = W[i];
    __syncthreads();
    const int lane = threadIdx.x & 63;   // output column
    const int rb   = threadIdx.x >> 6;   // row within block group (0..3)
    for (int row = blockIdx.x * 4 + rb; row < n; row += gridDim.x * 4) {
        const float* xr = X + (long)row * K;
        float a0 = 0.f, a1 = 0.f, a2 = 0.f, a3 = 0.f;
#pragma unroll
        for (int k = 0; k < K; k += 4) {
            a0 += xr[k + 0] * Ws[(k + 0) * 64 + lane];
            a1 += xr[k + 1] * Ws[(k + 1) * 64 + lane];
            a2 += xr[k + 2] * Ws[(k + 2) * 64 + lane];
            a3 += xr[k + 3] * Ws[(k + 3) * 64 + lane];
        }
        Y[(long)row * 64 + lane] = (a0 + a1) + (a2 + a3);
    }
}

// ---------------- edge scatter: one wave per edge ----------------
__global__ __launch_bounds__(256) void scatter_edges(const float* __restrict__ H,
                                                     const int* __restrict__ src,
                                                     const int* __restrict__ dst,
                                                     const float* __restrict__ dinv,
                                                     float* __restrict__ out, int E) {
    long idx = (long)blockIdx.x * blockDim.x + threadIdx.x;
    long e = idx >> 6;
    if (e >= E) return;
    int j = threadIdx.x & 63;
    int s = src[e];
    int d = dst[e];
    float w = dinv[s] * dinv[d];
    atomicAdd(&out[(long)d * 64 + j], H[(long)s * 64 + j] * w);
}

// self-loop + bias + relu
__global__ __launch_bounds__(256) void finish_relu(const float* __restrict__ H,
                                                   const float* __restrict__ bias,
                                                   const float* __restrict__ dinv,
                                                   float* __restrict__ out, int n) {
    long idx = (long)blockIdx.x * blockDim.x + threadIdx.x;
    long v = idx >> 6;
    if (v >= n) return;
    int j = threadIdx.x & 63;
    float di = dinv[v];
    float val = out[idx] + H[idx] * di * di + bias[j];
    out[idx] = fmaxf(val, 0.f);
}

// ---------------- pooling: z[v]=dot(G[v,:],Wl); pool[batch[v]]+=z; cnt++ ----------------
__global__ __launch_bounds__(256) void pool_dot(const float* __restrict__ G,
                                                const float* __restrict__ Wl,
                                                const int* __restrict__ batch,
                                                float* __restrict__ pool,
                                                float* __restrict__ cnt, int n) {
    long idx = (long)blockIdx.x * blockDim.x + threadIdx.x;
    long v = idx >> 6;
    if (v >= n) return;
    int j = threadIdx.x & 63;
    float val = G[idx] * Wl[j];
#pragma unroll
    for (int off = 32; off > 0; off >>= 1) val += __shfl_down(val, off, 64);
    if (j == 0) {
        int g = batch[v];
        atomicAdd(&pool[g], val);
        atomicAdd(&cnt[g], 1.0f);
    }
}

__global__ void final_out(const float* __restrict__ pool, const float* __restrict__ cnt,
                          const float* __restrict__ bl, float* __restrict__ out, int G) {
    int g = blockIdx.x * blockDim.x + threadIdx.x;
    if (g < G) out[g] = pool[g] / fmaxf(cnt[g], 1.0f) + bl[0];
}

extern "C" void kernel_launch(void* const* d_in, const int* in_sizes, int n_in,
                              void* d_out, int out_size, void* d_ws, size_t ws_size,
                              hipStream_t stream) {
    const float* x  = (const float*)d_in[0];
    const float* W1 = (const float*)d_in[1];
    const float* b1 = (const float*)d_in[2];
    const float* W2 = (const float*)d_in[3];
    const float* b2 = (const float*)d_in[4];
    const float* Wl = (const float*)d_in[5];
    const float* bl = (const float*)d_in[6];
    const int* edge_index = (const int*)d_in[7];
    const int* batch      = (const int*)d_in[8];

    const int n = in_sizes[0] / 128;   // 50000
    const int E = in_sizes[7] / 2;     // 800000
    const int G = out_size;            // 256
    const int* src = edge_index;
    const int* dst = edge_index + E;

    char* ws = (char*)d_ws;
    size_t dinv_bytes = ((size_t)n * sizeof(float) + 255) & ~(size_t)255;
    float* dinv = (float*)ws;
    float* bufA = (float*)(ws + dinv_bytes);          // n*64 floats
    float* bufB = bufA + (size_t)n * 64;              // n*64 floats
    float* pool = bufB + (size_t)n * 64;              // G floats
    float* cnt  = pool + G;                           // G floats
    const size_t nb = (size_t)n * 64 * sizeof(float);

    const int T = 256;
    // degrees (shared by both layers)
    deg_init<<<(n + T - 1) / T, T, 0, stream>>>(dinv, n);
    deg_edges<<<(E + T - 1) / T, T, 0, stream>>>(dst, dinv, E);
    deg_fin<<<(n + T - 1) / T, T, 0, stream>>>(dinv, n);

    // layer 1
    gemm_rm64<128><<<1024, T, 0, stream>>>(x, W1, bufA, n);      // h1 = x@W1
    hipMemsetAsync(bufB, 0, nb, stream);
    {
        long total = (long)E * 64;
        scatter_edges<<<(int)((total + T - 1) / T), T, 0, stream>>>(bufA, src, dst, dinv, bufB, E);
    }
    finish_relu<<<(int)(((long)n * 64 + T - 1) / T), T, 0, stream>>>(bufA, b1, dinv, bufB, n);

    // layer 2
    gemm_rm64<64><<<1024, T, 0, stream>>>(bufB, W2, bufA, n);    // h2pre = g1@W2
    hipMemsetAsync(bufB, 0, nb, stream);
    {
        long total = (long)E * 64;
        scatter_edges<<<(int)((total + T - 1) / T), T, 0, stream>>>(bufA, src, dst, dinv, bufB, E);
    }
    finish_relu<<<(int)(((long)n * 64 + T - 1) / T), T, 0, stream>>>(bufA, b2, dinv, bufB, n);

    // pooling + head
    hipMemsetAsync(pool, 0, 2 * G * sizeof(float), stream);
    pool_dot<<<(int)(((long)n * 64 + T - 1) / T), T, 0, stream>>>(bufB, Wl, batch, pool, cnt, n);
    final_out<<<(G + T - 1) / T, T, 0, stream>>>(pool, cnt, bl, (float*)d_out, G);
}

// Round 2
// 548.794 us; speedup vs baseline: 1.3451x; 1.3451x over previous
//
#include <hip/hip_runtime.h>
#include <math.h>

// ---------------- degree / dinv ----------------
__global__ void deg_init(float* __restrict__ deg, int n) {
    int v = blockIdx.x * blockDim.x + threadIdx.x;
    if (v < n) deg[v] = 1.0f;  // self-loop
}

__global__ void deg_edges(const int* __restrict__ dst, float* __restrict__ deg, int E) {
    int e = blockIdx.x * blockDim.x + threadIdx.x;
    if (e < E) atomicAdd(&deg[dst[e]], 1.0f);
}

__global__ void deg_fin(float* __restrict__ deg, int n) {
    int v = blockIdx.x * blockDim.x + threadIdx.x;
    if (v < n) deg[v] = 1.0f / sqrtf(deg[v]);
}

// ---------------- GEMM: Y[n,64] = X[n,K] @ W[K,64] ----------------
template <int K>
__global__ __launch_bounds__(256) void gemm_rm64(const float* __restrict__ X,
                                                 const float* __restrict__ W,
                                                 float* __restrict__ Y, int n) {
    __shared__ float Ws[K * 64];
    for (int i = threadIdx.x; i < K * 64; i += 256) Ws[i] = W[i];
    __syncthreads();
    const int lane = threadIdx.x & 63;   // output column
    const int rb   = threadIdx.x >> 6;   // row within block group (0..3)
    for (int row = blockIdx.x * 4 + rb; row < n; row += gridDim.x * 4) {
        const float* xr = X + (long)row * K;
        float a0 = 0.f, a1 = 0.f, a2 = 0.f, a3 = 0.f;
#pragma unroll
        for (int k = 0; k < K; k += 4) {
            a0 += xr[k + 0] * Ws[(k + 0) * 64 + lane];
            a1 += xr[k + 1] * Ws[(k + 1) * 64 + lane];
            a2 += xr[k + 2] * Ws[(k + 2) * 64 + lane];
            a3 += xr[k + 3] * Ws[(k + 3) * 64 + lane];
        }
        Y[(long)row * 64 + lane] = (a0 + a1) + (a2 + a3);
    }
}

// ---------------- edge scatter: one wave per edge ----------------
__global__ __launch_bounds__(256) void scatter_edges(const float* __restrict__ H,
                                                     const int* __restrict__ src,
                                                     const int* __restrict__ dst,
                                                     const float* __restrict__ dinv,
                                                     float* __restrict__ out, int E) {
    long idx = (long)blockIdx.x * blockDim.x + threadIdx.x;
    long e = idx >> 6;
    if (e >= E) return;
    int j = threadIdx.x & 63;
    int s = src[e];
    int d = dst[e];
    float w = dinv[s] * dinv[d];
    atomicAdd(&out[(long)d * 64 + j], H[(long)s * 64 + j] * w);
}

// self-loop + bias + relu
__global__ __launch_bounds__(256) void finish_relu(const float* __restrict__ H,
                                                   const float* __restrict__ bias,
                                                   const float* __restrict__ dinv,
                                                   float* __restrict__ out, int n) {
    long idx = (long)blockIdx.x * blockDim.x + threadIdx.x;
    long v = idx >> 6;
    if (v >= n) return;
    int j = threadIdx.x & 63;
    float di = dinv[v];
    float val = out[idx] + H[idx] * di * di + bias[j];
    out[idx] = fmaxf(val, 0.f);
}

// ---------------- pooling with LDS privatization ----------------
// z[v] = dot(H2[v,:], Wl); pool[batch[v]] += z; cnt[batch[v]] += 1
// batch is SORTED -> naive global atomics all hit the same hot address.
// Privatize per-block in LDS (256 bins), flush once per block.
__global__ __launch_bounds__(256) void pool_dot_priv(const float* __restrict__ H,
                                                     const float* __restrict__ Wl,
                                                     const int* __restrict__ batch,
                                                     float* __restrict__ pool,
                                                     float* __restrict__ cnt,
                                                     int n, int ngraphs) {
    __shared__ float lp[256];
    __shared__ float lc[256];
    lp[threadIdx.x] = 0.f;
    lc[threadIdx.x] = 0.f;
    __syncthreads();
    const int j  = threadIdx.x & 63;
    const int wv = threadIdx.x >> 6;  // 0..3
    for (long v = (long)blockIdx.x * 4 + wv; v < n; v += (long)gridDim.x * 4) {
        float val = H[v * 64 + j] * Wl[j];
#pragma unroll
        for (int off = 32; off > 0; off >>= 1) val += __shfl_down(val, off, 64);
        if (j == 0) {
            int g = batch[v];
            atomicAdd(&lp[g], val);
            atomicAdd(&lc[g], 1.0f);
        }
    }
    __syncthreads();
    int t = threadIdx.x;
    if (t < ngraphs && lc[t] != 0.f) {
        atomicAdd(&pool[t], lp[t]);
        atomicAdd(&cnt[t], lc[t]);
    }
}

__global__ void final_out(const float* __restrict__ pool, const float* __restrict__ cnt,
                          const float* __restrict__ bl, float* __restrict__ out, int G) {
    int g = blockIdx.x * blockDim.x + threadIdx.x;
    if (g < G) out[g] = pool[g] / fmaxf(cnt[g], 1.0f) + bl[0];
}

extern "C" void kernel_launch(void* const* d_in, const int* in_sizes, int n_in,
                              void* d_out, int out_size, void* d_ws, size_t ws_size,
                              hipStream_t stream) {
    const float* x  = (const float*)d_in[0];
    const float* W1 = (const float*)d_in[1];
    const float* b1 = (const float*)d_in[2];
    const float* W2 = (const float*)d_in[3];
    const float* b2 = (const float*)d_in[4];
    const float* Wl = (const float*)d_in[5];
    const float* bl = (const float*)d_in[6];
    const int* edge_index = (const int*)d_in[7];
    const int* batch      = (const int*)d_in[8];

    const int n = in_sizes[0] / 128;   // 50000
    const int E = in_sizes[7] / 2;     // 800000
    const int G = out_size;            // 256
    const int* src = edge_index;
    const int* dst = edge_index + E;

    char* ws = (char*)d_ws;
    size_t dinv_bytes = ((size_t)n * sizeof(float) + 255) & ~(size_t)255;
    float* dinv = (float*)ws;
    float* bufA = (float*)(ws + dinv_bytes);          // n*64 floats
    float* bufB = bufA + (size_t)n * 64;              // n*64 floats
    float* pool = bufB + (size_t)n * 64;              // G floats
    float* cnt  = pool + G;                           // G floats
    const size_t nb = (size_t)n * 64 * sizeof(float);

    const int T = 256;
    // degrees (shared by both layers)
    deg_init<<<(n + T - 1) / T, T, 0, stream>>>(dinv, n);
    deg_edges<<<(E + T - 1) / T, T, 0, stream>>>(dst, dinv, E);
    deg_fin<<<(n + T - 1) / T, T, 0, stream>>>(dinv, n);

    // layer 1
    gemm_rm64<128><<<1024, T, 0, stream>>>(x, W1, bufA, n);      // h1 = x@W1
    hipMemsetAsync(bufB, 0, nb, stream);
    {
        long total = (long)E * 64;
        scatter_edges<<<(int)((total + T - 1) / T), T, 0, stream>>>(bufA, src, dst, dinv, bufB, E);
    }
    finish_relu<<<(int)(((long)n * 64 + T - 1) / T), T, 0, stream>>>(bufA, b1, dinv, bufB, n);

    // layer 2
    gemm_rm64<64><<<1024, T, 0, stream>>>(bufB, W2, bufA, n);    // h2pre = g1@W2
    hipMemsetAsync(bufB, 0, nb, stream);
    {
        long total = (long)E * 64;
        scatter_edges<<<(int)((total + T - 1) / T), T, 0, stream>>>(bufA, src, dst, dinv, bufB, E);
    }
    finish_relu<<<(int)(((long)n * 64 + T - 1) / T), T, 0, stream>>>(bufA, b2, dinv, bufB, n);

    // pooling + head
    hipMemsetAsync(pool, 0, 2 * G * sizeof(float), stream);
    pool_dot_priv<<<256, T, 0, stream>>>(bufB, Wl, batch, pool, cnt, n, G);
    final_out<<<(G + T - 1) / T, T, 0, stream>>>(pool, cnt, bl, (float*)d_out, G);
}

// Round 3
// 476.696 us; speedup vs baseline: 1.5486x; 1.1512x over previous
//
#include <hip/hip_runtime.h>
#include <math.h>

// ---------------- CSR build ----------------
__global__ void hist_dst(const int* __restrict__ dst, int* __restrict__ cnt, int E) {
    int e = blockIdx.x * blockDim.x + threadIdx.x;
    if (e < E) atomicAdd(&cnt[dst[e]], 1);
}

__global__ void dinv_from_cnt(const int* __restrict__ cnt, float* __restrict__ dinv, int n) {
    int v = blockIdx.x * blockDim.x + threadIdx.x;
    if (v < n) dinv[v] = rsqrtf((float)(cnt[v] + 1));  // +1 self-loop
}

// single-block exclusive scan over n counts -> rowptr[0..n], cursor copy
__global__ __launch_bounds__(1024) void scan_rowptr(const int* __restrict__ cnt,
                                                    int* __restrict__ rowptr,
                                                    int* __restrict__ cursor, int n) {
    __shared__ int buf[1024];
    __shared__ int base;
    if (threadIdx.x == 0) base = 0;
    __syncthreads();
    for (int start = 0; start < n; start += 1024) {
        int i = start + threadIdx.x;
        int v = (i < n) ? cnt[i] : 0;
        buf[threadIdx.x] = v;
        __syncthreads();
#pragma unroll
        for (int off = 1; off < 1024; off <<= 1) {
            int t = (threadIdx.x >= off) ? buf[threadIdx.x - off] : 0;
            __syncthreads();
            buf[threadIdx.x] += t;
            __syncthreads();
        }
        int excl = buf[threadIdx.x] - v;
        if (i < n) { rowptr[i] = base + excl; cursor[i] = base + excl; }
        __syncthreads();
        if (threadIdx.x == 0) base += buf[1023];
        __syncthreads();
    }
    if (threadIdx.x == 0) rowptr[n] = base;
}

__global__ void fill_csr(const int* __restrict__ src, const int* __restrict__ dst,
                         const float* __restrict__ dinv, int* __restrict__ cursor,
                         int* __restrict__ col, float* __restrict__ val, int E) {
    int e = blockIdx.x * blockDim.x + threadIdx.x;
    if (e >= E) return;
    int s = src[e], d = dst[e];
    int p = atomicAdd(&cursor[d], 1);
    col[p] = s;
    val[p] = dinv[s] * dinv[d];
}

// ---------------- GEMM: Y[n,64] = X[n,K] @ W[K,64] ----------------
template <int K>
__global__ __launch_bounds__(256) void gemm_rm64(const float* __restrict__ X,
                                                 const float* __restrict__ W,
                                                 float* __restrict__ Y, int n) {
    __shared__ float Ws[K * 64];
    for (int i = threadIdx.x; i < K * 64; i += 256) Ws[i] = W[i];
    __syncthreads();
    const int lane = threadIdx.x & 63;
    const int rb   = threadIdx.x >> 6;
    for (int row = blockIdx.x * 4 + rb; row < n; row += gridDim.x * 4) {
        const float* xr = X + (long)row * K;
        float a0 = 0.f, a1 = 0.f, a2 = 0.f, a3 = 0.f;
#pragma unroll
        for (int k = 0; k < K; k += 4) {
            a0 += xr[k + 0] * Ws[(k + 0) * 64 + lane];
            a1 += xr[k + 1] * Ws[(k + 1) * 64 + lane];
            a2 += xr[k + 2] * Ws[(k + 2) * 64 + lane];
            a3 += xr[k + 3] * Ws[(k + 3) * 64 + lane];
        }
        Y[(long)row * 64 + lane] = (a0 + a1) + (a2 + a3);
    }
}

// ---------------- CSR aggregation, one wave per node, fused bias+relu ----------------
__global__ __launch_bounds__(256) void agg_relu(const float* __restrict__ H,
                                                const int* __restrict__ rowptr,
                                                const int* __restrict__ col,
                                                const float* __restrict__ val,
                                                const float* __restrict__ dinv,
                                                const float* __restrict__ bias,
                                                float* __restrict__ out, int n) {
    long idx = (long)blockIdx.x * blockDim.x + threadIdx.x;
    long v = idx >> 6;
    if (v >= n) return;
    int j = threadIdx.x & 63;
    float di = dinv[v];
    float acc = H[v * 64 + j] * di * di + bias[j];
    int p0 = rowptr[v], p1 = rowptr[v + 1];
    for (int p = p0; p < p1; ++p) {
        int s = col[p];
        float w = val[p];
        acc += H[(long)s * 64 + j] * w;
    }
    out[idx] = fmaxf(acc, 0.f);
}

// ---------------- pooling with LDS privatization ----------------
__global__ __launch_bounds__(256) void pool_dot_priv(const float* __restrict__ H,
                                                     const float* __restrict__ Wl,
                                                     const int* __restrict__ batch,
                                                     float* __restrict__ pool,
                                                     float* __restrict__ cnt,
                                                     int n, int ngraphs) {
    __shared__ float lp[256];
    __shared__ float lc[256];
    lp[threadIdx.x] = 0.f;
    lc[threadIdx.x] = 0.f;
    __syncthreads();
    const int j  = threadIdx.x & 63;
    const int wv = threadIdx.x >> 6;
    for (long v = (long)blockIdx.x * 4 + wv; v < n; v += (long)gridDim.x * 4) {
        float valx = H[v * 64 + j] * Wl[j];
#pragma unroll
        for (int off = 32; off > 0; off >>= 1) valx += __shfl_down(valx, off, 64);
        if (j == 0) {
            int g = batch[v];
            atomicAdd(&lp[g], valx);
            atomicAdd(&lc[g], 1.0f);
        }
    }
    __syncthreads();
    int t = threadIdx.x;
    if (t < ngraphs && lc[t] != 0.f) {
        atomicAdd(&pool[t], lp[t]);
        atomicAdd(&cnt[t], lc[t]);
    }
}

__global__ void final_out(const float* __restrict__ pool, const float* __restrict__ cnt,
                          const float* __restrict__ bl, float* __restrict__ out, int G) {
    int g = blockIdx.x * blockDim.x + threadIdx.x;
    if (g < G) out[g] = pool[g] / fmaxf(cnt[g], 1.0f) + bl[0];
}

extern "C" void kernel_launch(void* const* d_in, const int* in_sizes, int n_in,
                              void* d_out, int out_size, void* d_ws, size_t ws_size,
                              hipStream_t stream) {
    const float* x  = (const float*)d_in[0];
    const float* W1 = (const float*)d_in[1];
    const float* b1 = (const float*)d_in[2];
    const float* W2 = (const float*)d_in[3];
    const float* b2 = (const float*)d_in[4];
    const float* Wl = (const float*)d_in[5];
    const float* bl = (const float*)d_in[6];
    const int* edge_index = (const int*)d_in[7];
    const int* batch      = (const int*)d_in[8];

    const int n = in_sizes[0] / 128;   // 50000
    const int E = in_sizes[7] / 2;     // 800000
    const int G = out_size;            // 256
    const int* src = edge_index;
    const int* dst = edge_index + E;

    char* ws = (char*)d_ws;
    size_t off = 0;
    auto alloc = [&](size_t bytes) { void* p = ws + off; off = (off + bytes + 255) & ~(size_t)255; return p; };
    int*   cntv   = (int*)  alloc((size_t)n * 4);
    float* dinv   = (float*)alloc((size_t)n * 4);
    int*   rowptr = (int*)  alloc((size_t)(n + 1) * 4);
    int*   cursor = (int*)  alloc((size_t)n * 4);
    int*   col    = (int*)  alloc((size_t)E * 4);
    float* val    = (float*)alloc((size_t)E * 4);
    float* bufA   = (float*)alloc((size_t)n * 64 * 4);
    float* bufB   = (float*)alloc((size_t)n * 64 * 4);
    float* pool   = (float*)alloc((size_t)G * 4);
    float* cnt    = (float*)alloc((size_t)G * 4);

    const int T = 256;
    // ---- CSR build (shared by both layers) ----
    hipMemsetAsync(cntv, 0, (size_t)n * 4, stream);
    hist_dst<<<(E + T - 1) / T, T, 0, stream>>>(dst, cntv, E);
    dinv_from_cnt<<<(n + T - 1) / T, T, 0, stream>>>(cntv, dinv, n);
    scan_rowptr<<<1, 1024, 0, stream>>>(cntv, rowptr, cursor, n);
    fill_csr<<<(E + T - 1) / T, T, 0, stream>>>(src, dst, dinv, cursor, col, val, E);

    // ---- layer 1 ----
    gemm_rm64<128><<<1024, T, 0, stream>>>(x, W1, bufA, n);
    agg_relu<<<(int)(((long)n * 64 + T - 1) / T), T, 0, stream>>>(bufA, rowptr, col, val, dinv, b1, bufB, n);

    // ---- layer 2 ----
    gemm_rm64<64><<<1024, T, 0, stream>>>(bufB, W2, bufA, n);
    agg_relu<<<(int)(((long)n * 64 + T - 1) / T), T, 0, stream>>>(bufA, rowptr, col, val, dinv, b2, bufB, n);

    // ---- pooling + head ----
    hipMemsetAsync(pool, 0, 2 * (size_t)G * 4, stream);
    pool_dot_priv<<<256, T, 0, stream>>>(bufB, Wl, batch, pool, cnt, n, G);
    final_out<<<(G + T - 1) / T, T, 0, stream>>>(pool, cnt, bl, (float*)d_out, G);
}

// Round 4
// 382.235 us; speedup vs baseline: 1.9313x; 1.2471x over previous
//
#include <hip/hip_runtime.h>
#include <math.h>

// ---------------- CSR build ----------------
__global__ void hist_dst(const int* __restrict__ dst, int* __restrict__ cnt, int E) {
    int e = blockIdx.x * blockDim.x + threadIdx.x;
    if (e < E) atomicAdd(&cnt[dst[e]], 1);
}

__global__ void dinv_from_cnt(const int* __restrict__ cnt, float* __restrict__ dinv, int n) {
    int v = blockIdx.x * blockDim.x + threadIdx.x;
    if (v < n) dinv[v] = rsqrtf((float)(cnt[v] + 1));  // +1 self-loop
}

// ---- hierarchical scan: 256-elem chunks ----
__global__ __launch_bounds__(256) void scan1(const int* __restrict__ cnt,
                                             int* __restrict__ excl,
                                             int* __restrict__ sums, int n) {
    int i = blockIdx.x * 256 + threadIdx.x;
    int v = (i < n) ? cnt[i] : 0;
    int lane = threadIdx.x & 63;
    int w = threadIdx.x >> 6;
    int s = v;
#pragma unroll
    for (int off = 1; off < 64; off <<= 1) {
        int t = __shfl_up(s, off, 64);
        if (lane >= off) s += t;
    }
    __shared__ int wsum[4];
    if (lane == 63) wsum[w] = s;
    __syncthreads();
    int woff = 0;
#pragma unroll
    for (int k = 0; k < 3; ++k) if (k < w) woff += wsum[k];
    int incl = s + woff;
    if (i < n) excl[i] = incl - v;
    if (threadIdx.x == 255) sums[blockIdx.x] = incl;
}

// exclusive scan of nb (<=256) chunk sums, in place
__global__ __launch_bounds__(256) void scan2(int* __restrict__ sums, int nb) {
    int t = threadIdx.x;
    int v = (t < nb) ? sums[t] : 0;
    int lane = t & 63;
    int w = t >> 6;
    int s = v;
#pragma unroll
    for (int off = 1; off < 64; off <<= 1) {
        int u = __shfl_up(s, off, 64);
        if (lane >= off) s += u;
    }
    __shared__ int wsum[4];
    if (lane == 63) wsum[w] = s;
    __syncthreads();
    int woff = 0;
#pragma unroll
    for (int k = 0; k < 3; ++k) if (k < w) woff += wsum[k];
    int incl = s + woff;
    if (t < nb) sums[t] = incl - v;  // exclusive
}

__global__ __launch_bounds__(256) void scan3(const int* __restrict__ excl,
                                             const int* __restrict__ sums,
                                             int* __restrict__ rowptr,
                                             int* __restrict__ cursor, int n, int E) {
    int i = blockIdx.x * 256 + threadIdx.x;
    if (i < n) {
        int r = excl[i] + sums[i >> 8];
        rowptr[i] = r;
        cursor[i] = r;
    }
    if (i == n) rowptr[n] = E;
}

__global__ void fill_csr(const int* __restrict__ src, const int* __restrict__ dst,
                         const float* __restrict__ dinv, int* __restrict__ cursor,
                         int* __restrict__ col, float* __restrict__ val, int E) {
    int e = blockIdx.x * blockDim.x + threadIdx.x;
    if (e >= E) return;
    int s = src[e], d = dst[e];
    int p = atomicAdd(&cursor[d], 1);
    col[p] = s;
    val[p] = dinv[s] * dinv[d];
}

// ---------------- GEMM: Y[n,64] = X[n,K] @ W[K,64] ----------------
template <int K>
__global__ __launch_bounds__(256) void gemm_rm64(const float* __restrict__ X,
                                                 const float* __restrict__ W,
                                                 float* __restrict__ Y, int n) {
    __shared__ float Ws[K * 64];
    for (int i = threadIdx.x; i < K * 64; i += 256) Ws[i] = W[i];
    __syncthreads();
    const int lane = threadIdx.x & 63;
    const int rb   = threadIdx.x >> 6;
    for (int row = blockIdx.x * 4 + rb; row < n; row += gridDim.x * 4) {
        const float* xr = X + (long)row * K;
        float a0 = 0.f, a1 = 0.f, a2 = 0.f, a3 = 0.f;
#pragma unroll
        for (int k = 0; k < K; k += 4) {
            a0 += xr[k + 0] * Ws[(k + 0) * 64 + lane];
            a1 += xr[k + 1] * Ws[(k + 1) * 64 + lane];
            a2 += xr[k + 2] * Ws[(k + 2) * 64 + lane];
            a3 += xr[k + 3] * Ws[(k + 3) * 64 + lane];
        }
        Y[(long)row * 64 + lane] = (a0 + a1) + (a2 + a3);
    }
}

// ---------------- CSR aggregation, one wave per node, fused bias+relu ----------------
__global__ __launch_bounds__(256) void agg_relu(const float* __restrict__ H,
                                                const int* __restrict__ rowptr,
                                                const int* __restrict__ col,
                                                const float* __restrict__ val,
                                                const float* __restrict__ dinv,
                                                const float* __restrict__ bias,
                                                float* __restrict__ out, int n) {
    long idx = (long)blockIdx.x * blockDim.x + threadIdx.x;
    long v = idx >> 6;
    if (v >= n) return;
    int j = threadIdx.x & 63;
    float di = dinv[v];
    float acc = H[v * 64 + j] * di * di + bias[j];
    int p0 = rowptr[v], p1 = rowptr[v + 1];
    for (int p = p0; p < p1; ++p) {
        int s = col[p];
        float w = val[p];
        acc += H[(long)s * 64 + j] * w;
    }
    out[idx] = fmaxf(acc, 0.f);
}

// ---------------- pooling with LDS privatization ----------------
__global__ __launch_bounds__(256) void pool_dot_priv(const float* __restrict__ H,
                                                     const float* __restrict__ Wl,
                                                     const int* __restrict__ batch,
                                                     float* __restrict__ pool,
                                                     float* __restrict__ cnt,
                                                     int n, int ngraphs) {
    __shared__ float lp[256];
    __shared__ float lc[256];
    lp[threadIdx.x] = 0.f;
    lc[threadIdx.x] = 0.f;
    __syncthreads();
    const int j  = threadIdx.x & 63;
    const int wv = threadIdx.x >> 6;
    for (long v = (long)blockIdx.x * 4 + wv; v < n; v += (long)gridDim.x * 4) {
        float valx = H[v * 64 + j] * Wl[j];
#pragma unroll
        for (int off = 32; off > 0; off >>= 1) valx += __shfl_down(valx, off, 64);
        if (j == 0) {
            int g = batch[v];
            atomicAdd(&lp[g], valx);
            atomicAdd(&lc[g], 1.0f);
        }
    }
    __syncthreads();
    int t = threadIdx.x;
    if (t < ngraphs && lc[t] != 0.f) {
        atomicAdd(&pool[t], lp[t]);
        atomicAdd(&cnt[t], lc[t]);
    }
}

__global__ void final_out(const float* __restrict__ pool, const float* __restrict__ cnt,
                          const float* __restrict__ bl, float* __restrict__ out, int G) {
    int g = blockIdx.x * blockDim.x + threadIdx.x;
    if (g < G) out[g] = pool[g] / fmaxf(cnt[g], 1.0f) + bl[0];
}

extern "C" void kernel_launch(void* const* d_in, const int* in_sizes, int n_in,
                              void* d_out, int out_size, void* d_ws, size_t ws_size,
                              hipStream_t stream) {
    const float* x  = (const float*)d_in[0];
    const float* W1 = (const float*)d_in[1];
    const float* b1 = (const float*)d_in[2];
    const float* W2 = (const float*)d_in[3];
    const float* b2 = (const float*)d_in[4];
    const float* Wl = (const float*)d_in[5];
    const float* bl = (const float*)d_in[6];
    const int* edge_index = (const int*)d_in[7];
    const int* batch      = (const int*)d_in[8];

    const int n = in_sizes[0] / 128;   // 50000
    const int E = in_sizes[7] / 2;     // 800000
    const int G = out_size;            // 256
    const int* src = edge_index;
    const int* dst = edge_index + E;

    char* ws = (char*)d_ws;
    size_t off = 0;
    auto alloc = [&](size_t bytes) { void* p = ws + off; off = (off + bytes + 255) & ~(size_t)255; return p; };
    int*   cntv   = (int*)  alloc((size_t)n * 4);
    float* dinv   = (float*)alloc((size_t)n * 4);
    int*   rowptr = (int*)  alloc((size_t)(n + 1) * 4);
    int*   cursor = (int*)  alloc((size_t)n * 4);
    int*   excl   = (int*)  alloc((size_t)n * 4);
    int*   sums   = (int*)  alloc((size_t)256 * 4);
    int*   col    = (int*)  alloc((size_t)E * 4);
    float* val    = (float*)alloc((size_t)E * 4);
    float* bufA   = (float*)alloc((size_t)n * 64 * 4);
    float* bufB   = (float*)alloc((size_t)n * 64 * 4);
    float* pool   = (float*)alloc((size_t)G * 4);
    float* cnt    = (float*)alloc((size_t)G * 4);

    const int T = 256;
    const int nchunks = (n + 255) / 256;  // 196 <= 256
    // ---- CSR build (shared by both layers) ----
    hipMemsetAsync(cntv, 0, (size_t)n * 4, stream);
    hist_dst<<<(E + T - 1) / T, T, 0, stream>>>(dst, cntv, E);
    dinv_from_cnt<<<(n + T - 1) / T, T, 0, stream>>>(cntv, dinv, n);
    scan1<<<nchunks, T, 0, stream>>>(cntv, excl, sums, n);
    scan2<<<1, T, 0, stream>>>(sums, nchunks);
    scan3<<<(n + 1 + T - 1) / T, T, 0, stream>>>(excl, sums, rowptr, cursor, n, E);
    fill_csr<<<(E + T - 1) / T, T, 0, stream>>>(src, dst, dinv, cursor, col, val, E);

    // ---- layer 1 ----
    gemm_rm64<128><<<1024, T, 0, stream>>>(x, W1, bufA, n);
    agg_relu<<<(int)(((long)n * 64 + T - 1) / T), T, 0, stream>>>(bufA, rowptr, col, val, dinv, b1, bufB, n);

    // ---- layer 2 ----
    gemm_rm64<64><<<1024, T, 0, stream>>>(bufB, W2, bufA, n);
    agg_relu<<<(int)(((long)n * 64 + T - 1) / T), T, 0, stream>>>(bufA, rowptr, col, val, dinv, b2, bufB, n);

    // ---- pooling + head ----
    hipMemsetAsync(pool, 0, 2 * (size_t)G * 4, stream);
    pool_dot_priv<<<256, T, 0, stream>>>(bufB, Wl, batch, pool, cnt, n, G);
    final_out<<<(G + T - 1) / T, T, 0, stream>>>(pool, cnt, bl, (float*)d_out, G);
}

// Round 5
// 295.669 us; speedup vs baseline: 2.4967x; 1.2928x over previous
//
#include <hip/hip_runtime.h>
#include <math.h>

// ---------------- CSR build ----------------
__global__ void hist_dst(const int* __restrict__ dst, int* __restrict__ cnt, int E) {
    int e = blockIdx.x * blockDim.x + threadIdx.x;
    if (e < E) atomicAdd(&cnt[dst[e]], 1);
}

__global__ void dinv_from_cnt(const int* __restrict__ cnt, float* __restrict__ dinv, int n) {
    int v = blockIdx.x * blockDim.x + threadIdx.x;
    if (v < n) dinv[v] = rsqrtf((float)(cnt[v] + 1));  // +1 self-loop
}

// ---- hierarchical scan: 256-elem chunks ----
__global__ __launch_bounds__(256) void scan1(const int* __restrict__ cnt,
                                             int* __restrict__ excl,
                                             int* __restrict__ sums, int n) {
    int i = blockIdx.x * 256 + threadIdx.x;
    int v = (i < n) ? cnt[i] : 0;
    int lane = threadIdx.x & 63;
    int w = threadIdx.x >> 6;
    int s = v;
#pragma unroll
    for (int off = 1; off < 64; off <<= 1) {
        int t = __shfl_up(s, off, 64);
        if (lane >= off) s += t;
    }
    __shared__ int wsum[4];
    if (lane == 63) wsum[w] = s;
    __syncthreads();
    int woff = 0;
#pragma unroll
    for (int k = 0; k < 3; ++k) if (k < w) woff += wsum[k];
    int incl = s + woff;
    if (i < n) excl[i] = incl - v;
    if (threadIdx.x == 255) sums[blockIdx.x] = incl;
}

__global__ __launch_bounds__(256) void scan2(int* __restrict__ sums, int nb) {
    int t = threadIdx.x;
    int v = (t < nb) ? sums[t] : 0;
    int lane = t & 63;
    int w = t >> 6;
    int s = v;
#pragma unroll
    for (int off = 1; off < 64; off <<= 1) {
        int u = __shfl_up(s, off, 64);
        if (lane >= off) s += u;
    }
    __shared__ int wsum[4];
    if (lane == 63) wsum[w] = s;
    __syncthreads();
    int woff = 0;
#pragma unroll
    for (int k = 0; k < 3; ++k) if (k < w) woff += wsum[k];
    int incl = s + woff;
    if (t < nb) sums[t] = incl - v;  // exclusive
}

__global__ __launch_bounds__(256) void scan3(const int* __restrict__ excl,
                                             const int* __restrict__ sums,
                                             int* __restrict__ rowptr,
                                             int* __restrict__ cursor, int n, int E) {
    int i = blockIdx.x * 256 + threadIdx.x;
    if (i < n) {
        int r = excl[i] + sums[i >> 8];
        rowptr[i] = r;
        cursor[i] = r;
    }
    if (i == n) rowptr[n] = E;
}

// packed CSR payload: .x = src index (bit-cast), .y = edge weight
__global__ void fill_csr(const int* __restrict__ src, const int* __restrict__ dst,
                         const float* __restrict__ dinv, int* __restrict__ cursor,
                         float2* __restrict__ cv, int E) {
    int e = blockIdx.x * blockDim.x + threadIdx.x;
    if (e >= E) return;
    int s = src[e], d = dst[e];
    int p = atomicAdd(&cursor[d], 1);
    cv[p] = make_float2(__int_as_float(s), dinv[s] * dinv[d]);
}

// ---------------- GEMM: Y[n,64] = X[n,K] @ W[K,64] ----------------
template <int K>
__global__ __launch_bounds__(256) void gemm_rm64(const float* __restrict__ X,
                                                 const float* __restrict__ W,
                                                 float* __restrict__ Y, int n) {
    __shared__ float Ws[K * 64];
    for (int i = threadIdx.x; i < K * 64; i += 256) Ws[i] = W[i];
    __syncthreads();
    const int lane = threadIdx.x & 63;
    const int rb   = threadIdx.x >> 6;
    for (int row = blockIdx.x * 4 + rb; row < n; row += gridDim.x * 4) {
        const float* xr = X + (long)row * K;
        float a0 = 0.f, a1 = 0.f, a2 = 0.f, a3 = 0.f;
#pragma unroll
        for (int k = 0; k < K; k += 4) {
            a0 += xr[k + 0] * Ws[(k + 0) * 64 + lane];
            a1 += xr[k + 1] * Ws[(k + 1) * 64 + lane];
            a2 += xr[k + 2] * Ws[(k + 2) * 64 + lane];
            a3 += xr[k + 3] * Ws[(k + 3) * 64 + lane];
        }
        Y[(long)row * 64 + lane] = (a0 + a1) + (a2 + a3);
    }
}

// ---------------- CSR aggregation: one wave per node, unroll-4 MLP ----------------
__global__ __launch_bounds__(256) void agg_relu(const float* __restrict__ H,
                                                const int* __restrict__ rowptr,
                                                const float2* __restrict__ cv,
                                                const float* __restrict__ dinv,
                                                const float* __restrict__ bias,
                                                float* __restrict__ out, int n) {
    long idx = (long)blockIdx.x * blockDim.x + threadIdx.x;
    long v = idx >> 6;
    if (v >= n) return;
    int j = threadIdx.x & 63;
    float di = dinv[v];
    float acc0 = H[v * 64 + j] * di * di + bias[j];
    float acc1 = 0.f, acc2 = 0.f, acc3 = 0.f;
    int p0 = rowptr[v], p1 = rowptr[v + 1];
    int p = p0;
    for (; p + 4 <= p1; p += 4) {
        float2 m0 = cv[p + 0];
        float2 m1 = cv[p + 1];
        float2 m2 = cv[p + 2];
        float2 m3 = cv[p + 3];
        float h0 = H[(long)__float_as_int(m0.x) * 64 + j];
        float h1 = H[(long)__float_as_int(m1.x) * 64 + j];
        float h2 = H[(long)__float_as_int(m2.x) * 64 + j];
        float h3 = H[(long)__float_as_int(m3.x) * 64 + j];
        acc0 += h0 * m0.y;
        acc1 += h1 * m1.y;
        acc2 += h2 * m2.y;
        acc3 += h3 * m3.y;
    }
    for (; p < p1; ++p) {
        float2 m = cv[p];
        acc0 += H[(long)__float_as_int(m.x) * 64 + j] * m.y;
    }
    out[idx] = fmaxf((acc0 + acc1) + (acc2 + acc3), 0.f);
}

// ---------------- pooling with LDS privatization ----------------
__global__ __launch_bounds__(256) void pool_dot_priv(const float* __restrict__ H,
                                                     const float* __restrict__ Wl,
                                                     const int* __restrict__ batch,
                                                     float* __restrict__ pool,
                                                     float* __restrict__ cnt,
                                                     int n, int ngraphs) {
    __shared__ float lp[256];
    __shared__ float lc[256];
    lp[threadIdx.x] = 0.f;
    lc[threadIdx.x] = 0.f;
    __syncthreads();
    const int j  = threadIdx.x & 63;
    const int wv = threadIdx.x >> 6;
    for (long v = (long)blockIdx.x * 4 + wv; v < n; v += (long)gridDim.x * 4) {
        float valx = H[v * 64 + j] * Wl[j];
#pragma unroll
        for (int off = 32; off > 0; off >>= 1) valx += __shfl_down(valx, off, 64);
        if (j == 0) {
            int g = batch[v];
            atomicAdd(&lp[g], valx);
            atomicAdd(&lc[g], 1.0f);
        }
    }
    __syncthreads();
    int t = threadIdx.x;
    if (t < ngraphs && lc[t] != 0.f) {
        atomicAdd(&pool[t], lp[t]);
        atomicAdd(&cnt[t], lc[t]);
    }
}

__global__ void final_out(const float* __restrict__ pool, const float* __restrict__ cnt,
                          const float* __restrict__ bl, float* __restrict__ out, int G) {
    int g = blockIdx.x * blockDim.x + threadIdx.x;
    if (g < G) out[g] = pool[g] / fmaxf(cnt[g], 1.0f) + bl[0];
}

extern "C" void kernel_launch(void* const* d_in, const int* in_sizes, int n_in,
                              void* d_out, int out_size, void* d_ws, size_t ws_size,
                              hipStream_t stream) {
    const float* x  = (const float*)d_in[0];
    const float* W1 = (const float*)d_in[1];
    const float* b1 = (const float*)d_in[2];
    const float* W2 = (const float*)d_in[3];
    const float* b2 = (const float*)d_in[4];
    const float* Wl = (const float*)d_in[5];
    const float* bl = (const float*)d_in[6];
    const int* edge_index = (const int*)d_in[7];
    const int* batch      = (const int*)d_in[8];

    const int n = in_sizes[0] / 128;   // 50000
    const int E = in_sizes[7] / 2;     // 800000
    const int G = out_size;            // 256
    const int* src = edge_index;
    const int* dst = edge_index + E;

    char* ws = (char*)d_ws;
    size_t off = 0;
    auto alloc = [&](size_t bytes) { void* p = ws + off; off = (off + bytes + 255) & ~(size_t)255; return p; };
    int*    cntv   = (int*)   alloc((size_t)n * 4);
    float*  dinv   = (float*) alloc((size_t)n * 4);
    int*    rowptr = (int*)   alloc((size_t)(n + 1) * 4);
    int*    cursor = (int*)   alloc((size_t)n * 4);
    int*    excl   = (int*)   alloc((size_t)n * 4);
    int*    sums   = (int*)   alloc((size_t)256 * 4);
    float2* cv     = (float2*)alloc((size_t)E * 8);
    float*  bufA   = (float*) alloc((size_t)n * 64 * 4);
    float*  bufB   = (float*) alloc((size_t)n * 64 * 4);
    float*  pool   = (float*) alloc((size_t)G * 4);
    float*  cnt    = (float*) alloc((size_t)G * 4);

    const int T = 256;
    const int nchunks = (n + 255) / 256;  // 196 <= 256
    // ---- CSR build (shared by both layers) ----
    hipMemsetAsync(cntv, 0, (size_t)n * 4, stream);
    hist_dst<<<(E + T - 1) / T, T, 0, stream>>>(dst, cntv, E);
    dinv_from_cnt<<<(n + T - 1) / T, T, 0, stream>>>(cntv, dinv, n);
    scan1<<<nchunks, T, 0, stream>>>(cntv, excl, sums, n);
    scan2<<<1, T, 0, stream>>>(sums, nchunks);
    scan3<<<(n + 1 + T - 1) / T, T, 0, stream>>>(excl, sums, rowptr, cursor, n, E);
    fill_csr<<<(E + T - 1) / T, T, 0, stream>>>(src, dst, dinv, cursor, cv, E);

    // ---- layer 1 ----
    gemm_rm64<128><<<1024, T, 0, stream>>>(x, W1, bufA, n);
    agg_relu<<<(int)(((long)n * 64 + T - 1) / T), T, 0, stream>>>(bufA, rowptr, cv, dinv, b1, bufB, n);

    // ---- layer 2 ----
    gemm_rm64<64><<<1024, T, 0, stream>>>(bufB, W2, bufA, n);
    agg_relu<<<(int)(((long)n * 64 + T - 1) / T), T, 0, stream>>>(bufA, rowptr, cv, dinv, b2, bufB, n);

    // ---- pooling + head ----
    hipMemsetAsync(pool, 0, 2 * (size_t)G * 4, stream);
    pool_dot_priv<<<256, T, 0, stream>>>(bufB, Wl, batch, pool, cnt, n, G);
    final_out<<<(G + T - 1) / T, T, 0, stream>>>(pool, cnt, bl, (float*)d_out, G);
}

// Round 6
// 266.996 us; speedup vs baseline: 2.7649x; 1.1074x over previous
//
#include <hip/hip_runtime.h>
#include <math.h>

// ---------------- CSR build ----------------
__global__ void hist_dst(const int* __restrict__ dst, int* __restrict__ cnt, int E) {
    int e = blockIdx.x * blockDim.x + threadIdx.x;
    if (e < E) atomicAdd(&cnt[dst[e]], 1);
}

__global__ void dinv_from_cnt(const int* __restrict__ cnt, float* __restrict__ dinv, int n) {
    int v = blockIdx.x * blockDim.x + threadIdx.x;
    if (v < n) dinv[v] = rsqrtf((float)(cnt[v] + 1));  // +1 self-loop
}

// ---- hierarchical scan: 256-elem chunks ----
__global__ __launch_bounds__(256) void scan1(const int* __restrict__ cnt,
                                             int* __restrict__ excl,
                                             int* __restrict__ sums, int n) {
    int i = blockIdx.x * 256 + threadIdx.x;
    int v = (i < n) ? cnt[i] : 0;
    int lane = threadIdx.x & 63;
    int w = threadIdx.x >> 6;
    int s = v;
#pragma unroll
    for (int off = 1; off < 64; off <<= 1) {
        int t = __shfl_up(s, off, 64);
        if (lane >= off) s += t;
    }
    __shared__ int wsum[4];
    if (lane == 63) wsum[w] = s;
    __syncthreads();
    int woff = 0;
#pragma unroll
    for (int k = 0; k < 3; ++k) if (k < w) woff += wsum[k];
    int incl = s + woff;
    if (i < n) excl[i] = incl - v;
    if (threadIdx.x == 255) sums[blockIdx.x] = incl;
}

__global__ __launch_bounds__(256) void scan2(int* __restrict__ sums, int nb) {
    int t = threadIdx.x;
    int v = (t < nb) ? sums[t] : 0;
    int lane = t & 63;
    int w = t >> 6;
    int s = v;
#pragma unroll
    for (int off = 1; off < 64; off <<= 1) {
        int u = __shfl_up(s, off, 64);
        if (lane >= off) s += u;
    }
    __shared__ int wsum[4];
    if (lane == 63) wsum[w] = s;
    __syncthreads();
    int woff = 0;
#pragma unroll
    for (int k = 0; k < 3; ++k) if (k < w) woff += wsum[k];
    int incl = s + woff;
    if (t < nb) sums[t] = incl - v;  // exclusive
}

__global__ __launch_bounds__(256) void scan3(const int* __restrict__ excl,
                                             const int* __restrict__ sums,
                                             int* __restrict__ rowptr,
                                             int* __restrict__ cursor, int n, int E) {
    int i = blockIdx.x * 256 + threadIdx.x;
    if (i < n) {
        int r = excl[i] + sums[i >> 8];
        rowptr[i] = r;
        cursor[i] = r;
    }
    if (i == n) rowptr[n] = E;
}

// packed CSR payload: .x = src index (bit-cast), .y = edge weight
__global__ void fill_csr(const int* __restrict__ src, const int* __restrict__ dst,
                         const float* __restrict__ dinv, int* __restrict__ cursor,
                         float2* __restrict__ cv, int E) {
    int e = blockIdx.x * blockDim.x + threadIdx.x;
    if (e >= E) return;
    int s = src[e], d = dst[e];
    int p = atomicAdd(&cursor[d], 1);
    cv[p] = make_float2(__int_as_float(s), dinv[s] * dinv[d]);
}

// ---------------- GEMM: Y[n,64] = X[n,K] @ W[K,64] ----------------
// Lane owns output column: full W column in registers (K VGPRs).
// X staged 16 rows/block in LDS; k-loop = broadcast LDS float4 reads + FMAs.
template <int K>
__global__ __launch_bounds__(256) void gemm_wreg(const float* __restrict__ X,
                                                 const float* __restrict__ W,
                                                 float* __restrict__ Y, int n) {
    const int lane = threadIdx.x & 63;
    const int wv   = threadIdx.x >> 6;
    float wr[K];
#pragma unroll
    for (int k = 0; k < K; ++k) wr[k] = W[k * 64 + lane];   // coalesced per k
    __shared__ float xt[16 * K];
    for (long base = (long)blockIdx.x * 16; base < n; base += (long)gridDim.x * 16) {
        __syncthreads();
        // stage 16 rows of X, coalesced float4
#pragma unroll
        for (int c = 0; c < (16 * K) / 1024; ++c) {
            int l = (c * 256 + threadIdx.x) * 4;  // flat float index
            long gr = base + l / K;
            float4 vv = make_float4(0.f, 0.f, 0.f, 0.f);
            if (gr < n) vv = *(const float4*)&X[gr * K + (l % K)];
            *(float4*)&xt[l] = vv;
        }
        __syncthreads();
#pragma unroll
        for (int i = 0; i < 4; ++i) {
            int r = wv * 4 + i;
            const float4* xr4 = (const float4*)&xt[r * K];
            float acc0 = 0.f, acc1 = 0.f;
#pragma unroll
            for (int q = 0; q < K / 4; q += 2) {
                float4 xa = xr4[q];
                float4 xb = xr4[q + 1];
                acc0 += xa.x * wr[4 * q + 0];
                acc0 += xa.y * wr[4 * q + 1];
                acc0 += xa.z * wr[4 * q + 2];
                acc0 += xa.w * wr[4 * q + 3];
                acc1 += xb.x * wr[4 * q + 4];
                acc1 += xb.y * wr[4 * q + 5];
                acc1 += xb.z * wr[4 * q + 6];
                acc1 += xb.w * wr[4 * q + 7];
            }
            long gr = base + r;
            if (gr < n) Y[gr * 64 + lane] = acc0 + acc1;
        }
    }
}

// ---------------- CSR aggregation: one wave per node, unroll-4 MLP ----------------
__global__ __launch_bounds__(256) void agg_relu(const float* __restrict__ H,
                                                const int* __restrict__ rowptr,
                                                const float2* __restrict__ cv,
                                                const float* __restrict__ dinv,
                                                const float* __restrict__ bias,
                                                float* __restrict__ out, int n) {
    long idx = (long)blockIdx.x * blockDim.x + threadIdx.x;
    long v = idx >> 6;
    if (v >= n) return;
    int j = threadIdx.x & 63;
    float di = dinv[v];
    float acc0 = H[v * 64 + j] * di * di + bias[j];
    float acc1 = 0.f, acc2 = 0.f, acc3 = 0.f;
    int p0 = rowptr[v], p1 = rowptr[v + 1];
    int p = p0;
    for (; p + 4 <= p1; p += 4) {
        float2 m0 = cv[p + 0];
        float2 m1 = cv[p + 1];
        float2 m2 = cv[p + 2];
        float2 m3 = cv[p + 3];
        float h0 = H[(long)__float_as_int(m0.x) * 64 + j];
        float h1 = H[(long)__float_as_int(m1.x) * 64 + j];
        float h2 = H[(long)__float_as_int(m2.x) * 64 + j];
        float h3 = H[(long)__float_as_int(m3.x) * 64 + j];
        acc0 += h0 * m0.y;
        acc1 += h1 * m1.y;
        acc2 += h2 * m2.y;
        acc3 += h3 * m3.y;
    }
    for (; p < p1; ++p) {
        float2 m = cv[p];
        acc0 += H[(long)__float_as_int(m.x) * 64 + j] * m.y;
    }
    out[idx] = fmaxf((acc0 + acc1) + (acc2 + acc3), 0.f);
}

// ---------------- pooling with LDS privatization ----------------
__global__ __launch_bounds__(256) void pool_dot_priv(const float* __restrict__ H,
                                                     const float* __restrict__ Wl,
                                                     const int* __restrict__ batch,
                                                     float* __restrict__ pool,
                                                     float* __restrict__ cnt,
                                                     int n, int ngraphs) {
    __shared__ float lp[256];
    __shared__ float lc[256];
    lp[threadIdx.x] = 0.f;
    lc[threadIdx.x] = 0.f;
    __syncthreads();
    const int j  = threadIdx.x & 63;
    const int wv = threadIdx.x >> 6;
    for (long v = (long)blockIdx.x * 4 + wv; v < n; v += (long)gridDim.x * 4) {
        float valx = H[v * 64 + j] * Wl[j];
#pragma unroll
        for (int off = 32; off > 0; off >>= 1) valx += __shfl_down(valx, off, 64);
        if (j == 0) {
            int g = batch[v];
            atomicAdd(&lp[g], valx);
            atomicAdd(&lc[g], 1.0f);
        }
    }
    __syncthreads();
    int t = threadIdx.x;
    if (t < ngraphs && lc[t] != 0.f) {
        atomicAdd(&pool[t], lp[t]);
        atomicAdd(&cnt[t], lc[t]);
    }
}

__global__ void final_out(const float* __restrict__ pool, const float* __restrict__ cnt,
                          const float* __restrict__ bl, float* __restrict__ out, int G) {
    int g = blockIdx.x * blockDim.x + threadIdx.x;
    if (g < G) out[g] = pool[g] / fmaxf(cnt[g], 1.0f) + bl[0];
}

extern "C" void kernel_launch(void* const* d_in, const int* in_sizes, int n_in,
                              void* d_out, int out_size, void* d_ws, size_t ws_size,
                              hipStream_t stream) {
    const float* x  = (const float*)d_in[0];
    const float* W1 = (const float*)d_in[1];
    const float* b1 = (const float*)d_in[2];
    const float* W2 = (const float*)d_in[3];
    const float* b2 = (const float*)d_in[4];
    const float* Wl = (const float*)d_in[5];
    const float* bl = (const float*)d_in[6];
    const int* edge_index = (const int*)d_in[7];
    const int* batch      = (const int*)d_in[8];

    const int n = in_sizes[0] / 128;   // 50000
    const int E = in_sizes[7] / 2;     // 800000
    const int G = out_size;            // 256
    const int* src = edge_index;
    const int* dst = edge_index + E;

    char* ws = (char*)d_ws;
    size_t off = 0;
    auto alloc = [&](size_t bytes) { void* p = ws + off; off = (off + bytes + 255) & ~(size_t)255; return p; };
    int*    cntv   = (int*)   alloc((size_t)n * 4);
    float*  dinv   = (float*) alloc((size_t)n * 4);
    int*    rowptr = (int*)   alloc((size_t)(n + 1) * 4);
    int*    cursor = (int*)   alloc((size_t)n * 4);
    int*    excl   = (int*)   alloc((size_t)n * 4);
    int*    sums   = (int*)   alloc((size_t)256 * 4);
    float2* cv     = (float2*)alloc((size_t)E * 8);
    float*  bufA   = (float*) alloc((size_t)n * 64 * 4);
    float*  bufB   = (float*) alloc((size_t)n * 64 * 4);
    float*  pool   = (float*) alloc((size_t)G * 4);
    float*  cnt    = (float*) alloc((size_t)G * 4);

    const int T = 256;
    const int nchunks = (n + 255) / 256;  // 196 <= 256
    // ---- CSR build (shared by both layers) ----
    hipMemsetAsync(cntv, 0, (size_t)n * 4, stream);
    hist_dst<<<(E + T - 1) / T, T, 0, stream>>>(dst, cntv, E);
    dinv_from_cnt<<<(n + T - 1) / T, T, 0, stream>>>(cntv, dinv, n);
    scan1<<<nchunks, T, 0, stream>>>(cntv, excl, sums, n);
    scan2<<<1, T, 0, stream>>>(sums, nchunks);
    scan3<<<(n + 1 + T - 1) / T, T, 0, stream>>>(excl, sums, rowptr, cursor, n, E);
    fill_csr<<<(E + T - 1) / T, T, 0, stream>>>(src, dst, dinv, cursor, cv, E);

    const int gemm_grid = (n + 31) / 32;  // 2 tiles of 16 rows per block
    // ---- layer 1 ----
    gemm_wreg<128><<<gemm_grid, T, 0, stream>>>(x, W1, bufA, n);
    agg_relu<<<(int)(((long)n * 64 + T - 1) / T), T, 0, stream>>>(bufA, rowptr, cv, dinv, b1, bufB, n);

    // ---- layer 2 ----
    gemm_wreg<64><<<gemm_grid, T, 0, stream>>>(bufB, W2, bufA, n);
    agg_relu<<<(int)(((long)n * 64 + T - 1) / T), T, 0, stream>>>(bufA, rowptr, cv, dinv, b2, bufB, n);

    // ---- pooling + head ----
    hipMemsetAsync(pool, 0, 2 * (size_t)G * 4, stream);
    pool_dot_priv<<<256, T, 0, stream>>>(bufB, Wl, batch, pool, cnt, n, G);
    final_out<<<(G + T - 1) / T, T, 0, stream>>>(pool, cnt, bl, (float*)d_out, G);
}

// Round 7
// 227.523 us; speedup vs baseline: 3.2445x; 1.1735x over previous
//
#include <hip/hip_runtime.h>
#include <math.h>

// ---------------- small utils ----------------
__global__ void zero32(int* __restrict__ p, int n) {
    int i = blockIdx.x * blockDim.x + threadIdx.x;
    if (i < n) p[i] = 0;
}

// ---------------- CSR build ----------------
__global__ void hist_dst(const int* __restrict__ dst, int* __restrict__ cnt, int E) {
    int e = blockIdx.x * blockDim.x + threadIdx.x;
    if (e < E) atomicAdd(&cnt[dst[e]], 1);
}

__global__ void dinv_from_cnt(const int* __restrict__ cnt, float* __restrict__ dinv, int n) {
    int v = blockIdx.x * blockDim.x + threadIdx.x;
    if (v < n) dinv[v] = rsqrtf((float)(cnt[v] + 1));  // +1 self-loop
}

// ---- hierarchical scan: 256-elem chunks ----
__global__ __launch_bounds__(256) void scan1(const int* __restrict__ cnt,
                                             int* __restrict__ excl,
                                             int* __restrict__ sums, int n) {
    int i = blockIdx.x * 256 + threadIdx.x;
    int v = (i < n) ? cnt[i] : 0;
    int lane = threadIdx.x & 63;
    int w = threadIdx.x >> 6;
    int s = v;
#pragma unroll
    for (int off = 1; off < 64; off <<= 1) {
        int t = __shfl_up(s, off, 64);
        if (lane >= off) s += t;
    }
    __shared__ int wsum[4];
    if (lane == 63) wsum[w] = s;
    __syncthreads();
    int woff = 0;
#pragma unroll
    for (int k = 0; k < 3; ++k) if (k < w) woff += wsum[k];
    int incl = s + woff;
    if (i < n) excl[i] = incl - v;
    if (threadIdx.x == 255) sums[blockIdx.x] = incl;
}

__global__ __launch_bounds__(256) void scan2(int* __restrict__ sums, int nb) {
    int t = threadIdx.x;
    int v = (t < nb) ? sums[t] : 0;
    int lane = t & 63;
    int w = t >> 6;
    int s = v;
#pragma unroll
    for (int off = 1; off < 64; off <<= 1) {
        int u = __shfl_up(s, off, 64);
        if (lane >= off) s += u;
    }
    __shared__ int wsum[4];
    if (lane == 63) wsum[w] = s;
    __syncthreads();
    int woff = 0;
#pragma unroll
    for (int k = 0; k < 3; ++k) if (k < w) woff += wsum[k];
    int incl = s + woff;
    if (t < nb) sums[t] = incl - v;  // exclusive
}

__global__ __launch_bounds__(256) void scan3(const int* __restrict__ excl,
                                             const int* __restrict__ sums,
                                             int* __restrict__ rowptr,
                                             int* __restrict__ cursor, int n, int E) {
    int i = blockIdx.x * 256 + threadIdx.x;
    if (i < n) {
        int r = excl[i] + sums[i >> 8];
        rowptr[i] = r;
        cursor[i] = r;
    }
    if (i == n) rowptr[n] = E;
}

// packed CSR payload: .x = src index (bit-cast), .y = edge weight
__global__ void fill_csr(const int* __restrict__ src, const int* __restrict__ dst,
                         const float* __restrict__ dinv, int* __restrict__ cursor,
                         float2* __restrict__ cv, int E) {
    int e = blockIdx.x * blockDim.x + threadIdx.x;
    if (e >= E) return;
    int s = src[e], d = dst[e];
    int p = atomicAdd(&cursor[d], 1);
    cv[p] = make_float2(__int_as_float(s), dinv[s] * dinv[d]);
}

// ---------------- GEMM: Y[n,64] = X[n,K] @ W[K,64] ----------------
// Wave owns a row; lane owns output column. W column in VGPRs; row X
// loaded coalesced into per-lane regs and broadcast via v_readlane (SALU,
// parallel to VALU) -> inner loop is pure FMA, no LDS.
template <int K>
__global__ __launch_bounds__(256) void gemm_bcast(const float* __restrict__ X,
                                                  const float* __restrict__ W,
                                                  float* __restrict__ Y, int n) {
    const int lane = threadIdx.x & 63;
    const long wid = (((long)blockIdx.x * blockDim.x) + threadIdx.x) >> 6;
    const long nw  = ((long)gridDim.x * blockDim.x) >> 6;

    float wr[K];
#pragma unroll
    for (int k = 0; k < K; ++k) wr[k] = W[k * 64 + lane];  // coalesced per k

    long r = wid;
    if (r >= n) return;
    float xa = X[r * K + lane];
    float xb = 0.f;
    if constexpr (K > 64) xb = X[r * K + 64 + lane];

    while (true) {
        long rn = r + nw;
        bool more = rn < n;
        long rc = more ? rn : r;
        // prefetch next row while computing current
        float xan = X[rc * K + lane];
        float xbn = 0.f;
        if constexpr (K > 64) xbn = X[rc * K + 64 + lane];

        float a0 = 0.f, a1 = 0.f, a2 = 0.f, a3 = 0.f;
#pragma unroll
        for (int k = 0; k < 64; k += 4) {
            a0 = fmaf(__int_as_float(__builtin_amdgcn_readlane(__float_as_int(xa), k + 0)), wr[k + 0], a0);
            a1 = fmaf(__int_as_float(__builtin_amdgcn_readlane(__float_as_int(xa), k + 1)), wr[k + 1], a1);
            a2 = fmaf(__int_as_float(__builtin_amdgcn_readlane(__float_as_int(xa), k + 2)), wr[k + 2], a2);
            a3 = fmaf(__int_as_float(__builtin_amdgcn_readlane(__float_as_int(xa), k + 3)), wr[k + 3], a3);
        }
        if constexpr (K > 64) {
#pragma unroll
            for (int k = 0; k < 64; k += 4) {
                a0 = fmaf(__int_as_float(__builtin_amdgcn_readlane(__float_as_int(xb), k + 0)), wr[64 + k + 0], a0);
                a1 = fmaf(__int_as_float(__builtin_amdgcn_readlane(__float_as_int(xb), k + 1)), wr[64 + k + 1], a1);
                a2 = fmaf(__int_as_float(__builtin_amdgcn_readlane(__float_as_int(xb), k + 2)), wr[64 + k + 2], a2);
                a3 = fmaf(__int_as_float(__builtin_amdgcn_readlane(__float_as_int(xb), k + 3)), wr[64 + k + 3], a3);
            }
        }
        Y[r * 64 + lane] = (a0 + a1) + (a2 + a3);
        if (!more) break;
        r = rn;
        xa = xan;
        xb = xbn;
    }
}

// ---------------- CSR aggregation: one wave per node, unroll-4 MLP ----------------
__global__ __launch_bounds__(256) void agg_relu(const float* __restrict__ H,
                                                const int* __restrict__ rowptr,
                                                const float2* __restrict__ cv,
                                                const float* __restrict__ dinv,
                                                const float* __restrict__ bias,
                                                float* __restrict__ out, int n) {
    long idx = (long)blockIdx.x * blockDim.x + threadIdx.x;
    long v = idx >> 6;
    if (v >= n) return;
    int j = threadIdx.x & 63;
    float di = dinv[v];
    float acc0 = H[v * 64 + j] * di * di + bias[j];
    float acc1 = 0.f, acc2 = 0.f, acc3 = 0.f;
    int p0 = rowptr[v], p1 = rowptr[v + 1];
    int p = p0;
    for (; p + 4 <= p1; p += 4) {
        float2 m0 = cv[p + 0];
        float2 m1 = cv[p + 1];
        float2 m2 = cv[p + 2];
        float2 m3 = cv[p + 3];
        float h0 = H[(long)__float_as_int(m0.x) * 64 + j];
        float h1 = H[(long)__float_as_int(m1.x) * 64 + j];
        float h2 = H[(long)__float_as_int(m2.x) * 64 + j];
        float h3 = H[(long)__float_as_int(m3.x) * 64 + j];
        acc0 += h0 * m0.y;
        acc1 += h1 * m1.y;
        acc2 += h2 * m2.y;
        acc3 += h3 * m3.y;
    }
    for (; p < p1; ++p) {
        float2 m = cv[p];
        acc0 += H[(long)__float_as_int(m.x) * 64 + j] * m.y;
    }
    out[idx] = fmaxf((acc0 + acc1) + (acc2 + acc3), 0.f);
}

// ---------------- pooling: LDS-privatized partials, no global atomics ----------------
__global__ __launch_bounds__(256) void pool_part(const float* __restrict__ H,
                                                 const float* __restrict__ Wl,
                                                 const int* __restrict__ batch,
                                                 float* __restrict__ part,
                                                 float* __restrict__ partc, int n) {
    __shared__ float lp[256];
    __shared__ float lc[256];
    lp[threadIdx.x] = 0.f;
    lc[threadIdx.x] = 0.f;
    __syncthreads();
    const int j  = threadIdx.x & 63;
    const int wv = threadIdx.x >> 6;
    for (long v = (long)blockIdx.x * 4 + wv; v < n; v += (long)gridDim.x * 4) {
        float valx = H[v * 64 + j] * Wl[j];
#pragma unroll
        for (int off = 32; off > 0; off >>= 1) valx += __shfl_down(valx, off, 64);
        if (j == 0) {
            int g = batch[v];
            atomicAdd(&lp[g], valx);
            atomicAdd(&lc[g], 1.0f);
        }
    }
    __syncthreads();
    long o = (long)blockIdx.x * 256 + threadIdx.x;
    part[o]  = lp[threadIdx.x];
    partc[o] = lc[threadIdx.x];
}

// one block per graph: reduce partials, divide, add bias
__global__ __launch_bounds__(256) void pool_final(const float* __restrict__ part,
                                                  const float* __restrict__ partc,
                                                  const float* __restrict__ bl,
                                                  float* __restrict__ out, int nblk) {
    int g = blockIdx.x;
    int t = threadIdx.x;
    float s = 0.f, c = 0.f;
    for (int b = t; b < nblk; b += 256) {
        s += part[(long)b * 256 + g];
        c += partc[(long)b * 256 + g];
    }
    __shared__ float sp[256];
    __shared__ float sc[256];
    sp[t] = s;
    sc[t] = c;
    __syncthreads();
    for (int off = 128; off > 0; off >>= 1) {
        if (t < off) { sp[t] += sp[t + off]; sc[t] += sc[t + off]; }
        __syncthreads();
    }
    if (t == 0) out[g] = sp[0] / fmaxf(sc[0], 1.0f) + bl[0];
}

extern "C" void kernel_launch(void* const* d_in, const int* in_sizes, int n_in,
                              void* d_out, int out_size, void* d_ws, size_t ws_size,
                              hipStream_t stream) {
    const float* x  = (const float*)d_in[0];
    const float* W1 = (const float*)d_in[1];
    const float* b1 = (const float*)d_in[2];
    const float* W2 = (const float*)d_in[3];
    const float* b2 = (const float*)d_in[4];
    const float* Wl = (const float*)d_in[5];
    const float* bl = (const float*)d_in[6];
    const int* edge_index = (const int*)d_in[7];
    const int* batch      = (const int*)d_in[8];

    const int n = in_sizes[0] / 128;   // 50000
    const int E = in_sizes[7] / 2;     // 800000
    const int G = out_size;            // 256
    const int* src = edge_index;
    const int* dst = edge_index + E;

    char* ws = (char*)d_ws;
    size_t off = 0;
    auto alloc = [&](size_t bytes) { void* p = ws + off; off = (off + bytes + 255) & ~(size_t)255; return p; };
    int*    cntv   = (int*)   alloc((size_t)n * 4);
    float*  dinv   = (float*) alloc((size_t)n * 4);
    int*    rowptr = (int*)   alloc((size_t)(n + 1) * 4);
    int*    cursor = (int*)   alloc((size_t)n * 4);
    int*    excl   = (int*)   alloc((size_t)n * 4);
    int*    sums   = (int*)   alloc((size_t)256 * 4);
    float2* cv     = (float2*)alloc((size_t)E * 8);
    float*  bufA   = (float*) alloc((size_t)n * 64 * 4);
    float*  bufB   = (float*) alloc((size_t)n * 64 * 4);
    const int PBLK = 1024;
    float*  part   = (float*) alloc((size_t)PBLK * 256 * 4);
    float*  partc  = (float*) alloc((size_t)PBLK * 256 * 4);

    const int T = 256;
    const int nchunks = (n + 255) / 256;  // 196 <= 256
    // ---- CSR build (shared by both layers) ----
    zero32<<<(n + T - 1) / T, T, 0, stream>>>(cntv, n);
    hist_dst<<<(E + T - 1) / T, T, 0, stream>>>(dst, cntv, E);
    dinv_from_cnt<<<(n + T - 1) / T, T, 0, stream>>>(cntv, dinv, n);
    scan1<<<nchunks, T, 0, stream>>>(cntv, excl, sums, n);
    scan2<<<1, T, 0, stream>>>(sums, nchunks);
    scan3<<<(n + 1 + T - 1) / T, T, 0, stream>>>(excl, sums, rowptr, cursor, n, E);
    fill_csr<<<(E + T - 1) / T, T, 0, stream>>>(src, dst, dinv, cursor, cv, E);

    const int ggrid = 768;  // 3072 waves, ~16 rows each
    // ---- layer 1 ----
    gemm_bcast<128><<<ggrid, T, 0, stream>>>(x, W1, bufA, n);
    agg_relu<<<(int)(((long)n * 64 + T - 1) / T), T, 0, stream>>>(bufA, rowptr, cv, dinv, b1, bufB, n);

    // ---- layer 2 ----
    gemm_bcast<64><<<ggrid, T, 0, stream>>>(bufB, W2, bufA, n);
    agg_relu<<<(int)(((long)n * 64 + T - 1) / T), T, 0, stream>>>(bufA, rowptr, cv, dinv, b2, bufB, n);

    // ---- pooling + head ----
    pool_part<<<PBLK, T, 0, stream>>>(bufB, Wl, batch, part, partc, n);
    pool_final<<<G, T, 0, stream>>>(part, partc, bl, (float*)d_out, PBLK);
}